// Round 11
// baseline (442.859 us; speedup 1.0000x reference)
//
#include <hip/hip_runtime.h>
#include <math.h>

#define N_NODES 50000
#define N_EDGES 400000
#define N_GRAPHS 16
#define HEADS 4
#define NEG_SLOPE 0.2f

typedef __attribute__((ext_vector_type(8))) short short8;
typedef __attribute__((ext_vector_type(4))) float floatx4;
typedef _Float16 half_t;
typedef _Float16 half2_t __attribute__((ext_vector_type(2)));
typedef _Float16 half4_t __attribute__((ext_vector_type(4)));

__device__ __forceinline__ unsigned short f2bf(float x) {
    union { float f; unsigned int u; } v; v.f = x;
    unsigned int r = v.u + 0x7fffu + ((v.u >> 16) & 1u);
    return (unsigned short)(r >> 16);
}
__device__ __forceinline__ float bf2f(unsigned short b) {
    union { unsigned int u; float f; } v; v.u = ((unsigned int)b) << 16;
    return v.f;
}
__device__ __forceinline__ half2_t u2h2(unsigned int u) {
    union { unsigned int i; half2_t h; } v; v.i = u;
    return v.h;
}
__device__ __forceinline__ float fast_tanh(float x) {
    float e = __expf(2.f * x);
    return 1.f - 2.f / (e + 1.f);
}
__device__ __forceinline__ half2_t lrelu2(half2_t e) {
    half2_t s = e * (half2_t){(half_t)NEG_SLOPE, (half_t)NEG_SLOPE};
    return __builtin_elementwise_max(e, s);
}
__device__ __forceinline__ float dot2acc(half2_t a, half2_t b, float c) {
#if __has_builtin(__builtin_amdgcn_fdot2)
    return __builtin_amdgcn_fdot2(a, b, c, false);
#else
    return c + (float)a[0] * (float)b[0] + (float)a[1] * (float)b[1];
#endif
}

// ---------------- fused h0 + weight pack + zero cursor/hg ----------------
__global__ __launch_bounds__(256) void k_h0_pack(const float* __restrict__ feat,
                                                 const float* __restrict__ W_in,
                                                 const float* __restrict__ b_in,
                                                 unsigned short* __restrict__ h0,
                                                 const float* __restrict__ Wsrc,
                                                 const float* __restrict__ Wdst,
                                                 unsigned short* __restrict__ Wpack,
                                                 int* __restrict__ cursor,
                                                 float* __restrict__ hg) {
    int bid = blockIdx.x;
    if (bid < 12500) {
        int idx = bid * 256 + threadIdx.x;
        int node = idx >> 6, d = idx & 63;
        float acc = b_in[d];
        #pragma unroll
        for (int k = 0; k < 16; k++) acc += feat[node * 16 + k] * W_in[k * 64 + d];
        h0[idx] = f2bf(acc);
    } else if (bid < 12756) {
        int pb = bid - 12500;
        int mat = pb >> 7;
        int idx = (pb & 127) * 256 + threadIdx.x;
        const float* W = mat ? Wdst : Wsrc;
        int j = idx & 7;
        int lane = (idx >> 3) & 63;
        int q = (idx >> 9) & 3;
        int t = (idx >> 11) & 15;
        int col = t * 16 + (lane & 15);
        int k = q * 32 + (lane >> 4) * 8 + j;
        Wpack[mat * 32768 + idx] = f2bf(W[k * 256 + col]);
    } else if (bid < 12952) {
        int idx = (bid - 12756) * 256 + threadIdx.x;
        if (idx < N_NODES) cursor[idx] = 0;
    } else {
        for (int i = threadIdx.x; i < N_GRAPHS * 64; i += 256) hg[i] = 0.f;
    }
}

// ---------------- CSR build ----------------
__global__ __launch_bounds__(256) void k_hist(const int* __restrict__ dst, int* __restrict__ indeg, int e) {
    int i = blockIdx.x * 256 + threadIdx.x;
    if (i < e) atomicAdd(&indeg[dst[i]], 1);
}

__global__ __launch_bounds__(512) void k_scan_local(int* __restrict__ indeg,
                                                    int* __restrict__ offsets,
                                                    int* __restrict__ bsums, int n) {
    __shared__ int tmp[512];
    int t = threadIdx.x;
    int idx = blockIdx.x * 512 + t;
    int v = (idx < n) ? indeg[idx] : 0;
    tmp[t] = v;
    __syncthreads();
    #pragma unroll
    for (int off = 1; off < 512; off <<= 1) {
        int add = (t >= off) ? tmp[t - off] : 0;
        __syncthreads();
        tmp[t] += add;
        __syncthreads();
    }
    if (idx < n) { offsets[idx] = tmp[t] - v; indeg[idx] = 0; }
    if (t == 511) bsums[blockIdx.x] = tmp[511];
}

__global__ __launch_bounds__(512) void k_scan_add(int* __restrict__ offsets,
                                                  const int* __restrict__ bsums,
                                                  int nb, int n) {
    __shared__ int red[512];
    int t = threadIdx.x;
    int b = blockIdx.x;
    red[t] = (t < nb && t < b) ? bsums[t] : 0;
    __syncthreads();
    #pragma unroll
    for (int s = 256; s >= 1; s >>= 1) {
        if (t < s) red[t] += red[t + s];
        __syncthreads();
    }
    int prefix = red[0];
    int idx = b * 512 + t;
    if (idx < n) offsets[idx] += prefix;
    if (b == 0 && t == 0) offsets[n] = N_EDGES;
}

__global__ __launch_bounds__(256) void k_fill(const int* __restrict__ src, const int* __restrict__ dst,
                                              const int* __restrict__ offsets, int* __restrict__ cursor,
                                              int* __restrict__ csr_src, int e) {
    int i = blockIdx.x * 256 + threadIdx.x;
    if (i >= e) return;
    int d = dst[i];
    int slot = offsets[d] + atomicAdd(&cursor[d], 1);
    csr_src[slot] = src[i];
}

// ---------------- fused layer kernel: agg(l) [reads fs_in/fd_in -> h in LDS] + gemm(l+1)
// [writes fs_out/fd_out]. DOUBLE-BUFFERED fs/fd: agg gathers remote rows from the IN buffer
// while gemm overwrites only the OUT buffer -> no cross-block read/write race.
__global__ __launch_bounds__(256, 4) void k_layer(const unsigned short* __restrict__ h0,
                                                  const unsigned short* __restrict__ Wpack,
                                                  const float* __restrict__ bsrc,
                                                  const float* __restrict__ bdst,
                                                  const half_t* __restrict__ fs_in,
                                                  const half_t* __restrict__ fd_in,
                                                  half_t* __restrict__ fs_out,
                                                  half_t* __restrict__ fd_out,
                                                  const int* __restrict__ offsets,
                                                  const int* __restrict__ csr_src,
                                                  const float* __restrict__ attn,
                                                  unsigned short* __restrict__ hout,
                                                  int n, int has_agg, int has_gemm) {
    // row stride 88 ushorts = 176 B = 16x11: every row 16B-aligned (ds_read_b128-safe),
    // rows offset by 44 dwords -> max 2-way bank aliasing (free).
    __shared__ __align__(16) unsigned short htile[32][88];
    __shared__ __align__(16) half_t otile[32][264];          // 528 B stride (16x33)
    int wave = threadIdx.x >> 6, lane = threadIdx.x & 63;
    int node_base = blockIdx.x * 32;

    if (has_agg) {
        int slot = lane >> 5;
        int foff = ((lane >> 3) & 3) * 64 + (lane & 7) * 8;   // head*64 + dg*8
        unsigned boff = (unsigned)foff * 2;
        const char* fsb = (const char*)fs_in;
        half2_t at2[4];
        {
            float4 a0 = *(const float4*)(attn + foff);
            float4 a1 = *(const float4*)(attn + foff + 4);
            at2[0] = (half2_t){(half_t)a0.x, (half_t)a0.y};
            at2[1] = (half2_t){(half_t)a0.z, (half_t)a0.w};
            at2[2] = (half2_t){(half_t)a1.x, (half_t)a1.y};
            at2[3] = (half2_t){(half_t)a1.z, (half_t)a1.w};
        }
        for (int pass = 0; pass < 8; pass++) {
            int node = node_base + wave * 8 + pass;
            int lrow = wave * 8 + pass;
            if (node < n) {
                half2_t fd2[4];
                {
                    uint4 u = *(const uint4*)(fd_in + (size_t)node * 256 + foff);
                    fd2[0] = u2h2(u.x); fd2[1] = u2h2(u.y);
                    fd2[2] = u2h2(u.z); fd2[3] = u2h2(u.w);
                }
                float l = 0.f;
                half2_t zero2 = {(half_t)0.f, (half_t)0.f};
                half2_t acc2[4] = {zero2, zero2, zero2, zero2};
                int beg = offsets[node], end = offsets[node + 1];
                for (int j = beg; j < end; j += 8) {
                    int e0 = j + slot, e1 = j + 2 + slot, e2 = j + 4 + slot, e3 = j + 6 + slot;
                    bool v0 = e0 < end, v1 = e1 < end, v2 = e2 < end, v3 = e3 < end;
                    int s0 = csr_src[v0 ? e0 : beg];
                    int s1 = csr_src[v1 ? e1 : beg];
                    int s2 = csr_src[v2 ? e2 : beg];
                    int s3 = csr_src[v3 ? e3 : beg];
                    uint4 g0 = *(const uint4*)(fsb + (((unsigned)s0 << 9) + boff));
                    uint4 g1 = *(const uint4*)(fsb + (((unsigned)s1 << 9) + boff));
                    uint4 g2 = *(const uint4*)(fsb + (((unsigned)s2 << 9) + boff));
                    uint4 g3 = *(const uint4*)(fsb + (((unsigned)s3 << 9) + boff));
                    half2_t f0[4] = {u2h2(g0.x), u2h2(g0.y), u2h2(g0.z), u2h2(g0.w)};
                    half2_t f1[4] = {u2h2(g1.x), u2h2(g1.y), u2h2(g1.z), u2h2(g1.w)};
                    half2_t f2[4] = {u2h2(g2.x), u2h2(g2.y), u2h2(g2.z), u2h2(g2.w)};
                    half2_t f3[4] = {u2h2(g3.x), u2h2(g3.y), u2h2(g3.z), u2h2(g3.w)};
                    float p0 = 0.f, p1 = 0.f, p2 = 0.f, p3 = 0.f;
                    #pragma unroll
                    for (int k = 0; k < 4; k++) {
                        p0 = dot2acc(at2[k], lrelu2(f0[k] + fd2[k]), p0);
                        p1 = dot2acc(at2[k], lrelu2(f1[k] + fd2[k]), p1);
                        p2 = dot2acc(at2[k], lrelu2(f2[k] + fd2[k]), p2);
                        p3 = dot2acc(at2[k], lrelu2(f3[k] + fd2[k]), p3);
                    }
                    p0 += __shfl_xor(p0, 1, 64); p1 += __shfl_xor(p1, 1, 64);
                    p2 += __shfl_xor(p2, 1, 64); p3 += __shfl_xor(p3, 1, 64);
                    p0 += __shfl_xor(p0, 2, 64); p1 += __shfl_xor(p1, 2, 64);
                    p2 += __shfl_xor(p2, 2, 64); p3 += __shfl_xor(p3, 2, 64);
                    p0 += __shfl_xor(p0, 4, 64); p1 += __shfl_xor(p1, 4, 64);
                    p2 += __shfl_xor(p2, 4, 64); p3 += __shfl_xor(p3, 4, 64);
                    float w0 = v0 ? __expf(fminf(p0, 80.f)) : 0.f;
                    float w1 = v1 ? __expf(fminf(p1, 80.f)) : 0.f;
                    float w2 = v2 ? __expf(fminf(p2, 80.f)) : 0.f;
                    float w3 = v3 ? __expf(fminf(p3, 80.f)) : 0.f;
                    l += w0 + w1 + w2 + w3;
                    half_t hw0 = (half_t)w0, hw1 = (half_t)w1, hw2 = (half_t)w2, hw3 = (half_t)w3;
                    half2_t w02 = {hw0, hw0}, w12 = {hw1, hw1}, w22 = {hw2, hw2}, w32 = {hw3, hw3};
                    #pragma unroll
                    for (int k = 0; k < 4; k++) {
                        acc2[k] += w02 * f0[k];
                        acc2[k] += w12 * f1[k];
                        acc2[k] += w22 * f2[k];
                        acc2[k] += w32 * f3[k];
                    }
                }
                l += __shfl_xor(l, 32, 64);
                #pragma unroll
                for (int k = 0; k < 4; k++) {
                    float t = __builtin_bit_cast(float, acc2[k]);
                    t = __shfl_xor(t, 32, 64);
                    acc2[k] += __builtin_bit_cast(half2_t, t);
                }
                float inv = (l > 0.f) ? 1.f / l : 0.f;
                half2_t a0s = slot ? acc2[2] : acc2[0];
                half2_t a1s = slot ? acc2[3] : acc2[1];
                float o0 = fast_tanh((float)a0s[0] * inv);
                float o1 = fast_tanh((float)a0s[1] * inv);
                float o2 = fast_tanh((float)a1s[0] * inv);
                float o3 = fast_tanh((float)a1s[1] * inv);
                o0 += __shfl_xor(o0, 8, 64);  o0 += __shfl_xor(o0, 16, 64);
                o1 += __shfl_xor(o1, 8, 64);  o1 += __shfl_xor(o1, 16, 64);
                o2 += __shfl_xor(o2, 8, 64);  o2 += __shfl_xor(o2, 16, 64);
                o3 += __shfl_xor(o3, 8, 64);  o3 += __shfl_xor(o3, 16, 64);
                if ((lane & 31) < 8) {
                    ushort4 ov = {f2bf(o0), f2bf(o1), f2bf(o2), f2bf(o3)};
                    *(ushort4*)&htile[lrow][(lane & 7) * 8 + slot * 4] = ov;
                    if (!has_gemm)
                        *(ushort4*)(hout + (size_t)node * 64 + (lane & 7) * 8 + slot * 4) = ov;
                }
            } else if (has_gemm) {
                if ((lane & 31) < 8) {
                    ushort4 z = {0, 0, 0, 0};
                    *(ushort4*)&htile[lrow][(lane & 7) * 8 + slot * 4] = z;
                }
            }
        }
        __syncthreads();
    }

    if (has_gemm) {
        int quad = lane >> 4, m16 = lane & 15;
        int fhalf = wave & 1, ngrp = wave >> 1;
        int lrow = ngrp * 16 + m16;
        int r = node_base + lrow;
        if (r > n - 1) r = n - 1;

        floatx4 acc[2][8];
        #pragma unroll
        for (int m = 0; m < 2; m++)
            #pragma unroll
            for (int t = 0; t < 8; t++) acc[m][t] = (floatx4){0.f, 0.f, 0.f, 0.f};

        #pragma unroll
        for (int q = 0; q < 4; q++) {
            int kk = q * 32 + quad * 8;
            short8 x;
            if (has_agg && kk < 64) x = *(const short8*)&htile[lrow][kk];
            else x = *(const short8*)(h0 + (size_t)r * 64 + (kk & 63));
            #pragma unroll
            for (int t = 0; t < 8; t++) {
                int tt = fhalf * 8 + t;
                short8 w0 = *(const short8*)(Wpack + ((size_t)(tt * 4 + q) * 64 + lane) * 8);
                short8 w1 = *(const short8*)(Wpack + 32768 + ((size_t)(tt * 4 + q) * 64 + lane) * 8);
                acc[0][t] = __builtin_amdgcn_mfma_f32_16x16x32_bf16(w0, x, acc[0][t], 0, 0, 0);
                acc[1][t] = __builtin_amdgcn_mfma_f32_16x16x32_bf16(w1, x, acc[1][t], 0, 0, 0);
            }
        }
        #pragma unroll
        for (int mat = 0; mat < 2; mat++) {
            const float* bias = mat ? bdst : bsrc;
            half_t* outp = mat ? fd_out : fs_out;
            #pragma unroll
            for (int t = 0; t < 8; t++) {
                int fbase = (fhalf * 8 + t) * 16 + quad * 4;
                float4 bb = *(const float4*)(bias + fbase);
                half4_t ov = { (half_t)(acc[mat][t][0] + bb.x), (half_t)(acc[mat][t][1] + bb.y),
                               (half_t)(acc[mat][t][2] + bb.z), (half_t)(acc[mat][t][3] + bb.w) };
                *(half4_t*)&otile[lrow][fbase] = ov;
            }
            __syncthreads();
            for (int i = threadIdx.x; i < 1024; i += 256) {
                int row = i >> 5, seg = i & 31;
                int node = node_base + row;
                if (node < n)
                    *(uint4*)(outp + (size_t)node * 256 + seg * 8) = *(const uint4*)&otile[row][seg * 8];
            }
            __syncthreads();
        }
    }
}

// ---------------- graph readout: wave per 32 nodes, register accumulate ----------------
__global__ __launch_bounds__(256) void k_readout(const unsigned short* __restrict__ h,
                                                 const float* __restrict__ is_root,
                                                 const int* __restrict__ gid, float* __restrict__ hg, int n) {
    int wave = threadIdx.x >> 6, lane = threadIdx.x & 63;
    int start = blockIdx.x * 128 + wave * 32;
    if (start >= n) return;
    int stop = min(start + 32, n);
    float acc = 0.f;
    int cur = gid[start];
    for (int i = start; i < stop; i++) {
        int g = gid[i];
        if (g != cur) {
            atomicAdd(&hg[cur * 64 + lane], acc);
            acc = 0.f;
            cur = g;
        }
        acc += bf2f(h[(size_t)i * 64 + lane]) * is_root[i];
    }
    atomicAdd(&hg[cur * 64 + lane], acc);
}

__global__ __launch_bounds__(512) void k_out(const float* __restrict__ hg, const float* __restrict__ W_out,
                                             const float* __restrict__ b_out, float* __restrict__ out) {
    int t = threadIdx.x;
    if (t >= N_GRAPHS * 32) return;
    int b = t >> 5, c = t & 31;
    float a = b_out[c];
    #pragma unroll
    for (int d = 0; d < 64; d++) a += hg[b * 64 + d] * W_out[d * 32 + c];
    out[t] = a;
}

extern "C" void kernel_launch(void* const* d_in, const int* in_sizes, int n_in,
                              void* d_out, int out_size, void* d_ws, size_t ws_size,
                              hipStream_t stream) {
    const float* feat    = (const float*)d_in[0];
    const float* is_root = (const float*)d_in[1];
    const int*   src     = (const int*)d_in[2];
    const int*   dst     = (const int*)d_in[3];
    const int*   gid     = (const int*)d_in[4];
    const float* W_in    = (const float*)d_in[5];
    const float* b_in    = (const float*)d_in[6];
    const float* W_src   = (const float*)d_in[7];
    const float* b_src   = (const float*)d_in[8];
    const float* W_dst   = (const float*)d_in[9];
    const float* b_dst   = (const float*)d_in[10];
    const float* attn    = (const float*)d_in[11];
    const float* W_out   = (const float*)d_in[12];
    const float* b_out   = (const float*)d_in[13];
    float* out = (float*)d_out;

    char* ws = (char*)d_ws;
    size_t off = 0;
    auto take = [&](size_t bytes) -> char* {
        char* p = ws + off;
        off = (off + bytes + 255) & ~(size_t)255;
        return p;
    };
    half_t* fsA           = (half_t*)take((size_t)N_NODES * 256 * 2);
    half_t* fdA           = (half_t*)take((size_t)N_NODES * 256 * 2);
    half_t* fsB           = (half_t*)take((size_t)N_NODES * 256 * 2);
    half_t* fdB           = (half_t*)take((size_t)N_NODES * 256 * 2);
    unsigned short* h0    = (unsigned short*)take((size_t)N_NODES * 64 * 2);
    unsigned short* hB    = (unsigned short*)take((size_t)N_NODES * 64 * 2);
    unsigned short* Wpack = (unsigned short*)take((size_t)2 * 32768 * 2);
    float* hg             = (float*)take((size_t)N_GRAPHS * 64 * 4);
    int*   offsets        = (int*)take((size_t)(N_NODES + 1) * 4);
    int*   cursor         = (int*)take((size_t)N_NODES * 4);
    int*   csr_src        = (int*)take((size_t)N_EDGES * 4);
    int*   bsums          = (int*)take((size_t)512 * 4);

    const int n = N_NODES, e = N_EDGES;
    const int nb = (n + 511) / 512;  // 98
    const int nlb = (n + 31) / 32;   // 1563
    dim3 b256(256);

    k_h0_pack<<<dim3(12953), b256, 0, stream>>>(feat, W_in, b_in, h0, W_src, W_dst, Wpack,
                                                cursor, hg);

    // CSR build
    k_hist<<<dim3((e + 255) / 256), b256, 0, stream>>>(dst, cursor, e);
    k_scan_local<<<dim3(nb), dim3(512), 0, stream>>>(cursor, offsets, bsums, n);
    k_scan_add<<<dim3(nb), dim3(512), 0, stream>>>(offsets, bsums, nb, n);
    k_fill<<<dim3((e + 255) / 256), b256, 0, stream>>>(src, dst, offsets, cursor, csr_src, e);

    // layer pipeline (fs/fd double-buffered A<->B):
    // gemm0 -> A; agg(A)+gemm -> B; agg(B)+gemm -> A; agg(A)+gemm -> B; agg(B) -> hB
    k_layer<<<dim3(nlb), b256, 0, stream>>>(h0, Wpack, b_src, b_dst, fsA, fdA, fsA, fdA,
                                            offsets, csr_src, attn, hB, n, 0, 1);
    k_layer<<<dim3(nlb), b256, 0, stream>>>(h0, Wpack, b_src, b_dst, fsA, fdA, fsB, fdB,
                                            offsets, csr_src, attn, hB, n, 1, 1);
    k_layer<<<dim3(nlb), b256, 0, stream>>>(h0, Wpack, b_src, b_dst, fsB, fdB, fsA, fdA,
                                            offsets, csr_src, attn, hB, n, 1, 1);
    k_layer<<<dim3(nlb), b256, 0, stream>>>(h0, Wpack, b_src, b_dst, fsA, fdA, fsB, fdB,
                                            offsets, csr_src, attn, hB, n, 1, 1);
    k_layer<<<dim3(nlb), b256, 0, stream>>>(h0, Wpack, b_src, b_dst, fsB, fdB, fsB, fdB,
                                            offsets, csr_src, attn, hB, n, 1, 0);

    // readout + final projection
    k_readout<<<dim3((n + 127) / 128), b256, 0, stream>>>(hB, is_root, gid, hg, n);
    k_out<<<dim3(1), dim3(512), 0, stream>>>(hg, W_out, b_out, out);
}

// Round 12
// 412.628 us; speedup vs baseline: 1.0733x; 1.0733x over previous
//
#include <hip/hip_runtime.h>
#include <math.h>

#define N_NODES 50000
#define N_EDGES 400000
#define N_GRAPHS 16
#define HEADS 4
#define NEG_SLOPE 0.2f

typedef __attribute__((ext_vector_type(8))) short short8;
typedef __attribute__((ext_vector_type(4))) float floatx4;
typedef _Float16 half_t;
typedef _Float16 half2_t __attribute__((ext_vector_type(2)));
typedef _Float16 half4_t __attribute__((ext_vector_type(4)));

__device__ __forceinline__ unsigned short f2bf(float x) {
    union { float f; unsigned int u; } v; v.f = x;
    unsigned int r = v.u + 0x7fffu + ((v.u >> 16) & 1u);
    return (unsigned short)(r >> 16);
}
__device__ __forceinline__ float bf2f(unsigned short b) {
    union { unsigned int u; float f; } v; v.u = ((unsigned int)b) << 16;
    return v.f;
}
__device__ __forceinline__ half2_t u2h2(unsigned int u) {
    union { unsigned int i; half2_t h; } v; v.i = u;
    return v.h;
}
__device__ __forceinline__ float fast_tanh(float x) {
    float e = __expf(2.f * x);
    return 1.f - 2.f / (e + 1.f);
}
__device__ __forceinline__ half2_t lrelu2(half2_t e) {
    half2_t s = e * (half2_t){(half_t)NEG_SLOPE, (half_t)NEG_SLOPE};
    return __builtin_elementwise_max(e, s);
}
__device__ __forceinline__ float dot2acc(half2_t a, half2_t b, float c) {
#if __has_builtin(__builtin_amdgcn_fdot2)
    return __builtin_amdgcn_fdot2(a, b, c, false);
#else
    return c + (float)a[0] * (float)b[0] + (float)a[1] * (float)b[1];
#endif
}

// ---------------- fused h0 + weight pack + zero cursor/hg ----------------
__global__ __launch_bounds__(256) void k_h0_pack(const float* __restrict__ feat,
                                                 const float* __restrict__ W_in,
                                                 const float* __restrict__ b_in,
                                                 unsigned short* __restrict__ h0,
                                                 const float* __restrict__ Wsrc,
                                                 const float* __restrict__ Wdst,
                                                 unsigned short* __restrict__ Wpack,
                                                 int* __restrict__ cursor,
                                                 float* __restrict__ hg) {
    int bid = blockIdx.x;
    if (bid < 12500) {
        int idx = bid * 256 + threadIdx.x;
        int node = idx >> 6, d = idx & 63;
        float acc = b_in[d];
        #pragma unroll
        for (int k = 0; k < 16; k++) acc += feat[node * 16 + k] * W_in[k * 64 + d];
        h0[idx] = f2bf(acc);
    } else if (bid < 12756) {
        int pb = bid - 12500;
        int mat = pb >> 7;
        int idx = (pb & 127) * 256 + threadIdx.x;
        const float* W = mat ? Wdst : Wsrc;
        int j = idx & 7;
        int lane = (idx >> 3) & 63;
        int q = (idx >> 9) & 3;
        int t = (idx >> 11) & 15;
        int col = t * 16 + (lane & 15);
        int k = q * 32 + (lane >> 4) * 8 + j;
        Wpack[mat * 32768 + idx] = f2bf(W[k * 256 + col]);
    } else if (bid < 12952) {
        int idx = (bid - 12756) * 256 + threadIdx.x;
        if (idx < N_NODES) cursor[idx] = 0;
    } else {
        for (int i = threadIdx.x; i < N_GRAPHS * 64; i += 256) hg[i] = 0.f;
    }
}

// ---------------- CSR build ----------------
__global__ __launch_bounds__(256) void k_hist(const int* __restrict__ dst, int* __restrict__ indeg, int e) {
    int i = blockIdx.x * 256 + threadIdx.x;
    if (i < e) atomicAdd(&indeg[dst[i]], 1);
}

__global__ __launch_bounds__(512) void k_scan_local(int* __restrict__ indeg,
                                                    int* __restrict__ offsets,
                                                    int* __restrict__ bsums, int n) {
    __shared__ int tmp[512];
    int t = threadIdx.x;
    int idx = blockIdx.x * 512 + t;
    int v = (idx < n) ? indeg[idx] : 0;
    tmp[t] = v;
    __syncthreads();
    #pragma unroll
    for (int off = 1; off < 512; off <<= 1) {
        int add = (t >= off) ? tmp[t - off] : 0;
        __syncthreads();
        tmp[t] += add;
        __syncthreads();
    }
    if (idx < n) { offsets[idx] = tmp[t] - v; indeg[idx] = 0; }
    if (t == 511) bsums[blockIdx.x] = tmp[511];
}

__global__ __launch_bounds__(512) void k_scan_add(int* __restrict__ offsets,
                                                  const int* __restrict__ bsums,
                                                  int nb, int n) {
    __shared__ int red[512];
    int t = threadIdx.x;
    int b = blockIdx.x;
    red[t] = (t < nb && t < b) ? bsums[t] : 0;
    __syncthreads();
    #pragma unroll
    for (int s = 256; s >= 1; s >>= 1) {
        if (t < s) red[t] += red[t + s];
        __syncthreads();
    }
    int prefix = red[0];
    int idx = b * 512 + t;
    if (idx < n) offsets[idx] += prefix;
    if (b == 0 && t == 0) offsets[n] = N_EDGES;
}

__global__ __launch_bounds__(256) void k_fill(const int* __restrict__ src, const int* __restrict__ dst,
                                              const int* __restrict__ offsets, int* __restrict__ cursor,
                                              int* __restrict__ csr_src, int e) {
    int i = blockIdx.x * 256 + threadIdx.x;
    if (i >= e) return;
    int d = dst[i];
    int slot = offsets[d] + atomicAdd(&cursor[d], 1);
    csr_src[slot] = src[i];
}

// ---------------- fs/fd = [h|h0] @ {W_src,W_dst} + b  via MFMA, both mats/block ----------------
// wave = 16 nodes x 128 feats x 2 mats (shared x). Block 256 = 4 waves = 32 nodes x 256 feats.
// grid = ceil(n/32). LDS-staged coalesced stores.
__global__ __launch_bounds__(256) void k_gemm(const unsigned short* __restrict__ hcur,
                                              const unsigned short* __restrict__ h0,
                                              const unsigned short* __restrict__ Wpack,
                                              const float* __restrict__ bsrc,
                                              const float* __restrict__ bdst,
                                              half_t* __restrict__ fs,
                                              half_t* __restrict__ fd, int n) {
    __shared__ __align__(16) half_t otile[32][264];   // 528 B stride (16x33) - aligned, 2-way banks
    int wave = threadIdx.x >> 6, lane = threadIdx.x & 63;
    int quad = lane >> 4, m16 = lane & 15;
    int fhalf = wave & 1, ngrp = wave >> 1;
    int node_base = blockIdx.x * 32;
    int lrow = ngrp * 16 + m16;
    int r = node_base + lrow;
    if (r > n - 1) r = n - 1;

    // load x rows once (shared across both weight matrices)
    short8 x[4];
    #pragma unroll
    for (int q = 0; q < 4; q++) {
        int kk = q * 32 + quad * 8;
        const unsigned short* base = (kk < 64) ? (hcur + (size_t)r * 64 + kk)
                                               : (h0 + (size_t)r * 64 + (kk - 64));
        x[q] = *(const short8*)base;
    }

    floatx4 acc[2][8];
    #pragma unroll
    for (int m = 0; m < 2; m++)
        #pragma unroll
        for (int t = 0; t < 8; t++) acc[m][t] = (floatx4){0.f, 0.f, 0.f, 0.f};

    #pragma unroll
    for (int q = 0; q < 4; q++) {
        #pragma unroll
        for (int t = 0; t < 8; t++) {
            int tt = fhalf * 8 + t;
            short8 w0 = *(const short8*)(Wpack + ((size_t)(tt * 4 + q) * 64 + lane) * 8);
            short8 w1 = *(const short8*)(Wpack + 32768 + ((size_t)(tt * 4 + q) * 64 + lane) * 8);
            acc[0][t] = __builtin_amdgcn_mfma_f32_16x16x32_bf16(w0, x[q], acc[0][t], 0, 0, 0);
            acc[1][t] = __builtin_amdgcn_mfma_f32_16x16x32_bf16(w1, x[q], acc[1][t], 0, 0, 0);
        }
    }
    #pragma unroll
    for (int mat = 0; mat < 2; mat++) {
        const float* bias = mat ? bdst : bsrc;
        half_t* outp = mat ? fd : fs;
        #pragma unroll
        for (int t = 0; t < 8; t++) {
            int fbase = (fhalf * 8 + t) * 16 + quad * 4;
            float4 bb = *(const float4*)(bias + fbase);
            half4_t ov = { (half_t)(acc[mat][t][0] + bb.x), (half_t)(acc[mat][t][1] + bb.y),
                           (half_t)(acc[mat][t][2] + bb.z), (half_t)(acc[mat][t][3] + bb.w) };
            *(half4_t*)&otile[lrow][fbase] = ov;
        }
        __syncthreads();
        for (int i = threadIdx.x; i < 1024; i += 256) {
            int row = i >> 5, seg = i & 31;
            int node = node_base + row;
            if (node < n)
                *(uint4*)(outp + (size_t)node * 256 + seg * 8) = *(const uint4*)&otile[row][seg * 8];
        }
        __syncthreads();
    }
}

// ---------------- per-node aggregation: packed-f16, 2 slots x 4-edge unroll ----------------
// one wave per node; lane = (slot = lane>>5, head = (lane>>3)&3, dg = lane&7 -> dims dg*8..+7)
__global__ __launch_bounds__(256) void k_agg(const half_t* __restrict__ fs,
                                             const half_t* __restrict__ fd,
                                             const int* __restrict__ offsets,
                                             const int* __restrict__ csr_src,
                                             const float* __restrict__ attn,
                                             unsigned short* __restrict__ hout, int n) {
    int wave = threadIdx.x >> 6;
    int lane = threadIdx.x & 63;
    int node = blockIdx.x * 4 + wave;
    if (node >= n) return;
    int slot = lane >> 5;
    int foff = ((lane >> 3) & 3) * 64 + (lane & 7) * 8;   // head*64 + dg*8
    unsigned boff = (unsigned)foff * 2;
    const char* fsb = (const char*)fs;

    half2_t at2[4];
    {
        float4 a0 = *(const float4*)(attn + foff);
        float4 a1 = *(const float4*)(attn + foff + 4);
        at2[0] = (half2_t){(half_t)a0.x, (half_t)a0.y};
        at2[1] = (half2_t){(half_t)a0.z, (half_t)a0.w};
        at2[2] = (half2_t){(half_t)a1.x, (half_t)a1.y};
        at2[3] = (half2_t){(half_t)a1.z, (half_t)a1.w};
    }
    half2_t fd2[4];
    {
        uint4 u = *(const uint4*)(fd + (size_t)node * 256 + foff);
        fd2[0] = u2h2(u.x); fd2[1] = u2h2(u.y); fd2[2] = u2h2(u.z); fd2[3] = u2h2(u.w);
    }

    float l = 0.f;
    half2_t zero2 = {(half_t)0.f, (half_t)0.f};
    half2_t acc2[4] = {zero2, zero2, zero2, zero2};

    int beg = offsets[node], end = offsets[node + 1];
    for (int j = beg; j < end; j += 8) {
        int e0 = j + slot, e1 = j + 2 + slot, e2 = j + 4 + slot, e3 = j + 6 + slot;
        bool v0 = e0 < end, v1 = e1 < end, v2 = e2 < end, v3 = e3 < end;
        int s0 = csr_src[v0 ? e0 : beg];
        int s1 = csr_src[v1 ? e1 : beg];
        int s2 = csr_src[v2 ? e2 : beg];
        int s3 = csr_src[v3 ? e3 : beg];
        uint4 g0 = *(const uint4*)(fsb + (((unsigned)s0 << 9) + boff));
        uint4 g1 = *(const uint4*)(fsb + (((unsigned)s1 << 9) + boff));
        uint4 g2 = *(const uint4*)(fsb + (((unsigned)s2 << 9) + boff));
        uint4 g3 = *(const uint4*)(fsb + (((unsigned)s3 << 9) + boff));
        half2_t f0[4] = {u2h2(g0.x), u2h2(g0.y), u2h2(g0.z), u2h2(g0.w)};
        half2_t f1[4] = {u2h2(g1.x), u2h2(g1.y), u2h2(g1.z), u2h2(g1.w)};
        half2_t f2[4] = {u2h2(g2.x), u2h2(g2.y), u2h2(g2.z), u2h2(g2.w)};
        half2_t f3[4] = {u2h2(g3.x), u2h2(g3.y), u2h2(g3.z), u2h2(g3.w)};
        float p0 = 0.f, p1 = 0.f, p2 = 0.f, p3 = 0.f;
        #pragma unroll
        for (int k = 0; k < 4; k++) {
            p0 = dot2acc(at2[k], lrelu2(f0[k] + fd2[k]), p0);
            p1 = dot2acc(at2[k], lrelu2(f1[k] + fd2[k]), p1);
            p2 = dot2acc(at2[k], lrelu2(f2[k] + fd2[k]), p2);
            p3 = dot2acc(at2[k], lrelu2(f3[k] + fd2[k]), p3);
        }
        p0 += __shfl_xor(p0, 1, 64); p1 += __shfl_xor(p1, 1, 64);
        p2 += __shfl_xor(p2, 1, 64); p3 += __shfl_xor(p3, 1, 64);
        p0 += __shfl_xor(p0, 2, 64); p1 += __shfl_xor(p1, 2, 64);
        p2 += __shfl_xor(p2, 2, 64); p3 += __shfl_xor(p3, 2, 64);
        p0 += __shfl_xor(p0, 4, 64); p1 += __shfl_xor(p1, 4, 64);
        p2 += __shfl_xor(p2, 4, 64); p3 += __shfl_xor(p3, 4, 64);
        float w0 = v0 ? __expf(fminf(p0, 80.f)) : 0.f;
        float w1 = v1 ? __expf(fminf(p1, 80.f)) : 0.f;
        float w2 = v2 ? __expf(fminf(p2, 80.f)) : 0.f;
        float w3 = v3 ? __expf(fminf(p3, 80.f)) : 0.f;
        l += w0 + w1 + w2 + w3;
        half_t hw0 = (half_t)w0, hw1 = (half_t)w1, hw2 = (half_t)w2, hw3 = (half_t)w3;
        half2_t w02 = {hw0, hw0}, w12 = {hw1, hw1}, w22 = {hw2, hw2}, w32 = {hw3, hw3};
        #pragma unroll
        for (int k = 0; k < 4; k++) {
            acc2[k] += w02 * f0[k];
            acc2[k] += w12 * f1[k];
            acc2[k] += w22 * f2[k];
            acc2[k] += w32 * f3[k];
        }
    }
    // merge the two edge-slots
    l += __shfl_xor(l, 32, 64);
    #pragma unroll
    for (int k = 0; k < 4; k++) {
        float t = __builtin_bit_cast(float, acc2[k]);
        t = __shfl_xor(t, 32, 64);
        acc2[k] += __builtin_bit_cast(half2_t, t);
    }

    float inv = (l > 0.f) ? 1.f / l : 0.f;
    // slot-split epilogue
    half2_t a0 = slot ? acc2[2] : acc2[0];
    half2_t a1 = slot ? acc2[3] : acc2[1];
    float o0 = fast_tanh((float)a0[0] * inv);
    float o1 = fast_tanh((float)a0[1] * inv);
    float o2 = fast_tanh((float)a1[0] * inv);
    float o3 = fast_tanh((float)a1[1] * inv);
    o0 += __shfl_xor(o0, 8, 64);  o0 += __shfl_xor(o0, 16, 64);
    o1 += __shfl_xor(o1, 8, 64);  o1 += __shfl_xor(o1, 16, 64);
    o2 += __shfl_xor(o2, 8, 64);  o2 += __shfl_xor(o2, 16, 64);
    o3 += __shfl_xor(o3, 8, 64);  o3 += __shfl_xor(o3, 16, 64);
    if ((lane & 31) < 8) {
        ushort4 ov = {f2bf(o0), f2bf(o1), f2bf(o2), f2bf(o3)};
        *(ushort4*)(hout + (size_t)node * 64 + (lane & 7) * 8 + slot * 4) = ov;
    }
}

// ---------------- graph readout: wave per 32 nodes, register accumulate ----------------
__global__ __launch_bounds__(256) void k_readout(const unsigned short* __restrict__ h,
                                                 const float* __restrict__ is_root,
                                                 const int* __restrict__ gid, float* __restrict__ hg, int n) {
    int wave = threadIdx.x >> 6, lane = threadIdx.x & 63;
    int start = blockIdx.x * 128 + wave * 32;
    if (start >= n) return;
    int stop = min(start + 32, n);
    float acc = 0.f;
    int cur = gid[start];
    for (int i = start; i < stop; i++) {
        int g = gid[i];
        if (g != cur) {
            atomicAdd(&hg[cur * 64 + lane], acc);
            acc = 0.f;
            cur = g;
        }
        acc += bf2f(h[(size_t)i * 64 + lane]) * is_root[i];
    }
    atomicAdd(&hg[cur * 64 + lane], acc);
}

__global__ __launch_bounds__(512) void k_out(const float* __restrict__ hg, const float* __restrict__ W_out,
                                             const float* __restrict__ b_out, float* __restrict__ out) {
    int t = threadIdx.x;
    if (t >= N_GRAPHS * 32) return;
    int b = t >> 5, c = t & 31;
    float a = b_out[c];
    #pragma unroll
    for (int d = 0; d < 64; d++) a += hg[b * 64 + d] * W_out[d * 32 + c];
    out[t] = a;
}

extern "C" void kernel_launch(void* const* d_in, const int* in_sizes, int n_in,
                              void* d_out, int out_size, void* d_ws, size_t ws_size,
                              hipStream_t stream) {
    const float* feat    = (const float*)d_in[0];
    const float* is_root = (const float*)d_in[1];
    const int*   src     = (const int*)d_in[2];
    const int*   dst     = (const int*)d_in[3];
    const int*   gid     = (const int*)d_in[4];
    const float* W_in    = (const float*)d_in[5];
    const float* b_in    = (const float*)d_in[6];
    const float* W_src   = (const float*)d_in[7];
    const float* b_src   = (const float*)d_in[8];
    const float* W_dst   = (const float*)d_in[9];
    const float* b_dst   = (const float*)d_in[10];
    const float* attn    = (const float*)d_in[11];
    const float* W_out   = (const float*)d_in[12];
    const float* b_out   = (const float*)d_in[13];
    float* out = (float*)d_out;

    char* ws = (char*)d_ws;
    size_t off = 0;
    auto take = [&](size_t bytes) -> char* {
        char* p = ws + off;
        off = (off + bytes + 255) & ~(size_t)255;
        return p;
    };
    half_t* fs            = (half_t*)take((size_t)N_NODES * 256 * 2);
    half_t* fd            = (half_t*)take((size_t)N_NODES * 256 * 2);
    unsigned short* h0    = (unsigned short*)take((size_t)N_NODES * 64 * 2);
    unsigned short* hB    = (unsigned short*)take((size_t)N_NODES * 64 * 2);
    unsigned short* Wpack = (unsigned short*)take((size_t)2 * 32768 * 2);
    float* hg             = (float*)take((size_t)N_GRAPHS * 64 * 4);
    int*   offsets        = (int*)take((size_t)(N_NODES + 1) * 4);
    int*   cursor         = (int*)take((size_t)N_NODES * 4);
    int*   csr_src        = (int*)take((size_t)N_EDGES * 4);
    int*   bsums          = (int*)take((size_t)512 * 4);

    const int n = N_NODES, e = N_EDGES;
    const int nb = (n + 511) / 512;  // 98
    dim3 b256(256);

    k_h0_pack<<<dim3(12953), b256, 0, stream>>>(feat, W_in, b_in, h0, W_src, W_dst, Wpack,
                                                cursor, hg);

    // CSR build
    k_hist<<<dim3((e + 255) / 256), b256, 0, stream>>>(dst, cursor, e);
    k_scan_local<<<dim3(nb), dim3(512), 0, stream>>>(cursor, offsets, bsums, n);
    k_scan_add<<<dim3(nb), dim3(512), 0, stream>>>(offsets, bsums, nb, n);
    k_fill<<<dim3((e + 255) / 256), b256, 0, stream>>>(src, dst, offsets, cursor, csr_src, e);

    // 4 GATv2 layers (separate agg/gemm dispatches; dispatch boundary = sync)
    const unsigned short* hin = h0;
    for (int layer = 0; layer < 4; layer++) {
        k_gemm<<<dim3((n + 31) / 32), b256, 0, stream>>>(hin, h0, Wpack, b_src, b_dst, fs, fd, n);
        k_agg<<<dim3((n + 3) / 4), b256, 0, stream>>>(fs, fd, offsets, csr_src, attn, hB, n);
        hin = hB;
    }

    // readout + final projection
    k_readout<<<dim3((n + 127) / 128), b256, 0, stream>>>(hB, is_root, gid, hg, n);
    k_out<<<dim3(1), dim3(512), 0, stream>>>(hg, W_out, b_out, out);
}